// Round 19
// baseline (166.705 us; speedup 1.0000x reference)
//
#include <hip/hip_runtime.h>
#include <hip/hip_bf16.h>

#define IN_C  128
#define HID_C 64
#define OUT_C 32
#define NEG_SLOPE 0.2f
#define EPB1    2048     // edges per bin1 block
#define EPB2    2048     // records per bin2 part
#define BUCKETW 64       // dst nodes per region
#define RCAP    1536     // region capacity (mean 1023, +16 sigma)
#define SUPW    1024     // dst nodes per super-bucket
#define RCAP1   18432    // super capacity (mean 16327)
#define PARTS   9        // bin2 parts per super
#define CSTRIDE 16       // cursor padding (64B) to spread atomic lines
#define XS_LD   136      // LDS x-tile leading dim (ushorts): bank-spread pad

typedef short bf16x8 __attribute__((ext_vector_type(8)));
typedef float f32x4  __attribute__((ext_vector_type(4)));

__device__ __forceinline__ unsigned short f2bf(float f) {
    __hip_bfloat16 h = __float2bfloat16(f);
    return *(unsigned short*)&h;
}
__device__ __forceinline__ float bflo(unsigned int u) {
    return __uint_as_float(u << 16);
}
__device__ __forceinline__ float bfhi(unsigned int u) {
    return __uint_as_float(u & 0xffff0000u);
}

// ---------------------------------------------------------------------------
// Kernel 1 (FUSED, R18 proven): blocks [0, ngemm) = gemm+logits tile;
// blocks [ngemm, ngemm+nbin) = bin1 edge-binning (pure int).
// bcur1 pre-zeroed by hipMemsetAsync.
// ---------------------------------------------------------------------------
__global__ __launch_bounds__(256) void gemm_bin1_kernel(
    const float* __restrict__ x, const float* __restrict__ W,
    const float* __restrict__ att_src, const float* __restrict__ att_dst,
    __hip_bfloat16* __restrict__ hb,
    float* __restrict__ a_src, float* __restrict__ a_dst,
    const int* __restrict__ ei, int E,
    int* __restrict__ bcur1, unsigned* __restrict__ superbuf,
    int ngemm, int n_nodes)
{
    __shared__ __align__(16) unsigned char smem[8960];
    const int t = threadIdx.x;

    if ((int)blockIdx.x < ngemm) {
        // ---------------- gemm path ----------------
        unsigned short* xs = (unsigned short*)smem;          // 4352 B
        float (*redA)[16] = (float(*)[16])(smem + 4352);     // 256 B
        float (*redD)[16] = (float(*)[16])(smem + 4608);     // 256 B
        const int wv   = t >> 6;
        const int lane = t & 63;
        const int m16  = lane & 15;
        const int quad = lane >> 4;
        const int node0 = blockIdx.x * 16;
        const int nrows = min(16, n_nodes - node0);

        const int ncol = wv * 16 + m16;
        bf16x8 B[4];
#pragma unroll
        for (int k0 = 0; k0 < 4; ++k0)
#pragma unroll
            for (int j = 0; j < 8; ++j)
                B[k0][j] = (short)f2bf(W[(k0 * 32 + quad * 8 + j) * HID_C + ncol]);

        {
            const float4* xg = (const float4*)(x + (long)node0 * IN_C);
#pragma unroll
            for (int i = t; i < 512; i += 256) {
                const int row = i >> 5;
                const int c4  = i & 31;
                float4 v = (row < nrows) ? xg[i] : make_float4(0.f, 0.f, 0.f, 0.f);
                ushort4 u;
                u.x = f2bf(v.x); u.y = f2bf(v.y);
                u.z = f2bf(v.z); u.w = f2bf(v.w);
                *(ushort4*)(xs + row * XS_LD + c4 * 4) = u;
            }
        }
        __syncthreads();

        f32x4 C = {0.f, 0.f, 0.f, 0.f};
#pragma unroll
        for (int k0 = 0; k0 < 4; ++k0) {
            const bf16x8 A = *(const bf16x8*)(xs + m16 * XS_LD + k0 * 32 + quad * 8);
            C = __builtin_amdgcn_mfma_f32_16x16x32_bf16(A, B[k0], C, 0, 0, 0);
        }

#pragma unroll
        for (int r = 0; r < 4; ++r) {
            const int row = quad * 4 + r;
            if (row < nrows)
                hb[(long)(node0 + row) * HID_C + ncol] = __float2bfloat16(C[r]);
        }

        {
            const float av = att_src[ncol];
            const float dv = att_dst[ncol];
            float ps[4], pd[4];
#pragma unroll
            for (int r = 0; r < 4; ++r) { ps[r] = C[r] * av; pd[r] = C[r] * dv; }
#pragma unroll
            for (int off = 1; off <= 8; off <<= 1) {
#pragma unroll
                for (int r = 0; r < 4; ++r) {
                    ps[r] += __shfl_xor(ps[r], off, 64);
                    pd[r] += __shfl_xor(pd[r], off, 64);
                }
            }
            if (m16 == 0) {
#pragma unroll
                for (int r = 0; r < 4; ++r) {
                    redA[wv][quad * 4 + r] = ps[r];
                    redD[wv][quad * 4 + r] = pd[r];
                }
            }
        }
        __syncthreads();
        if (t < 16 && t < nrows) {
            a_src[node0 + t] = redA[0][t] + redA[1][t] + redA[2][t] + redA[3][t];
            a_dst[node0 + t] = redD[0][t] + redD[1][t] + redD[2][t] + redD[3][t];
        }
    } else {
        // ---------------- bin1 path (pure int) ----------------
        unsigned* stage = (unsigned*)smem;                   // 8192 B
        int* excl = (int*)(smem + 8192);
        int* cur  = (int*)(smem + 8448);
        int* gpos = (int*)(smem + 8704);

        const int base = (blockIdx.x - ngemm) * EPB1;
        const int nedge = min(EPB1, E - base);

        if (t < 64) excl[t] = 0;
        __syncthreads();

        for (int i = t; i < nedge; i += 256)
            atomicAdd(&excl[ei[E + base + i] >> 10], 1);
        __syncthreads();

        if (t < 64) {
            int c = excl[t], incl = c;
#pragma unroll
            for (int off = 1; off <= 32; off <<= 1) {
                int u = __shfl_up(incl, off, 64);
                if (t >= off) incl += u;
            }
            excl[t] = incl - c;
            cur[t]  = incl - c;
        }
        __syncthreads();

        for (int i = t; i < nedge; i += 256) {
            const int s = ei[base + i];
            const int d = ei[E + base + i];
            const int sq = d >> 10;
            const int pos = atomicAdd(&cur[sq], 1);
            stage[pos] = (unsigned)s | ((unsigned)(d & 1023) << 16)
                         | ((unsigned)sq << 26);
        }
        __syncthreads();

        if (t < 64) {
            const int c = cur[t] - excl[t];
            gpos[t] = (c > 0) ? atomicAdd(&bcur1[t * CSTRIDE], c) : 0;
        }
        __syncthreads();

        for (int i = t; i < nedge; i += 256) {
            const unsigned r = stage[i];
            const int sq = r >> 26;
            const int dp = gpos[sq] + (i - excl[sq]);
            if (dp < RCAP1) superbuf[(long)sq * RCAP1 + dp] = r;
        }
    }
}

// ---------------------------------------------------------------------------
// Kernel 2 (bin level 2, R16/R18 proven): super-buckets -> 64-dst regions.
// ---------------------------------------------------------------------------
__global__ __launch_bounds__(256) void bin2_kernel(
    const unsigned* __restrict__ superbuf, const int* __restrict__ bcur1,
    int* __restrict__ bcur2, unsigned* __restrict__ bucketbuf)
{
    __shared__ unsigned srt[EPB2];   // 8 KB
    __shared__ int cnt[16];
    __shared__ int rp[16];
    __shared__ int cur16[16];
    __shared__ int gpos[16];

    const int t    = threadIdx.x;
    const int sq   = blockIdx.x / PARTS;
    const int part = blockIdx.x % PARTS;
    const int tot  = min(bcur1[sq * CSTRIDE], RCAP1);
    const int beg  = part * EPB2;
    const int n    = min(EPB2, tot - beg);
    if (n <= 0) return;                       // block-uniform

    if (t < 16) cnt[t] = 0;
    __syncthreads();

    const unsigned* src = superbuf + (long)sq * RCAP1 + beg;

    for (int i = t; i < n; i += 256)
        atomicAdd(&cnt[(src[i] >> 22) & 15], 1);
    __syncthreads();

    if (t == 0) {
        int run = 0;
#pragma unroll
        for (int k = 0; k < 16; ++k) { rp[k] = run; cur16[k] = run; run += cnt[k]; }
    }
    __syncthreads();

    for (int i = t; i < n; i += 256) {
        const unsigned r = src[i];
        const int pos = atomicAdd(&cur16[(r >> 22) & 15], 1);
        srt[pos] = r;
    }
    __syncthreads();

    if (t < 16) {
        const int c = cnt[t];
        const int q2 = sq * 16 + t;
        gpos[t] = (c > 0) ? atomicAdd(&bcur2[q2 * CSTRIDE], c) : 0;
    }
    __syncthreads();

    for (int i = t; i < n; i += 256) {
        const unsigned r = srt[i];
        const int idx = (r >> 22) & 15;
        const int dp  = gpos[idx] + (i - rp[idx]);
        const int q2  = sq * 16 + idx;
        const unsigned nx = (r & 0xFFFFu) | (((r >> 16) & 63u) << 16);
        if (dp < RCAP) bucketbuf[(long)q2 * RCAP + dp] = nx;
    }
}

// ---------------------------------------------------------------------------
// Kernel 3: per-region aggregation + register epilogue — 1024 THREADS
// (16 waves/region): wave wv owns dloc = wv, wv+16, ... -> 4 serial
// gather rounds per wave (vs 8 at 512 thr); 2 blocks/CU = 32 waves/CU.
// Loop body identical to R16/R18's proven structure.
// ---------------------------------------------------------------------------
__global__ __launch_bounds__(1024) void bucket_agg_kernel(
    const unsigned* __restrict__ bucketbuf, const int* __restrict__ bcursor,
    const __hip_bfloat16* __restrict__ hb,
    const float* __restrict__ a_src, const float* __restrict__ a_dst,
    const float* __restrict__ bias_conv,
    const float* __restrict__ W_lin, const float* __restrict__ b_lin,
    float* __restrict__ out, int n_nodes)
{
    __shared__ unsigned srtL[RCAP];     // 6 KB
    __shared__ int cntd[BUCKETW];
    __shared__ int rp[BUCKETW + 1];
    __shared__ int curd[BUCKETW];

    const int t  = threadIdx.x;
    const int q  = blockIdx.x;
    const int d0 = q * BUCKETW;
    const int dmax = min(BUCKETW, n_nodes - d0);
    const int tot  = min(bcursor[q * CSTRIDE], RCAP);
    const int wv = t >> 6, lane = t & 63, g8 = lane >> 3, l = lane & 7;

    if (t < BUCKETW) cntd[t] = 0;
    __syncthreads();

    const unsigned* gsrc = bucketbuf + (long)q * RCAP;

    // pass 1: count per dloc
    for (int i = t; i < tot; i += 1024)
        atomicAdd(&cntd[(gsrc[i] >> 16) & 63], 1);
    __syncthreads();

    // one-wave scan of 64 counters
    if (t < 64) {
        int c = cntd[t], incl = c;
#pragma unroll
        for (int off = 1; off <= 32; off <<= 1) {
            int u = __shfl_up(incl, off, 64);
            if (t >= off) incl += u;
        }
        rp[t] = incl - c;
        curd[t] = incl - c;
        if (t == 63) rp[64] = incl;
    }
    __syncthreads();

    // pass 2: scatter into sorted LDS order (second read is L2-hot)
    for (int i = t; i < tot; i += 1024) {
        const unsigned r = gsrc[i];
        const int pos = atomicAdd(&curd[(r >> 16) & 63], 1);
        srtL[pos] = r;
    }
    __syncthreads();

    // per-lane epilogue constants
    float Wr[8][4];
#pragma unroll
    for (int kc = 0; kc < 8; ++kc)
#pragma unroll
        for (int kj = 0; kj < 4; ++kj)
            Wr[kc][kj] = W_lin[(l * 8 + kc) * OUT_C + g8 * 4 + kj];
    float biasR[8];
#pragma unroll
    for (int kc = 0; kc < 8; ++kc) biasR[kc] = bias_conv[l * 8 + kc];
    float blinR[4];
#pragma unroll
    for (int kj = 0; kj < 4; ++kj) blinR[kj] = b_lin[g8 * 4 + kj];

    const unsigned short* hbs = (const unsigned short*)hb;

    for (int dloc = wv; dloc < dmax; dloc += 16) {
        const int d = d0 + dloc;
        const float ad = a_dst[d];
        float A[8] = {0.f,0.f,0.f,0.f,0.f,0.f,0.f,0.f};
        float den = 0.f;
        if (g8 == 0) {        // self-loop on slot 0
            float e = a_src[d] + ad;
            e = (e >= 0.f) ? e : NEG_SLOPE * e;
            const float ws = __expf(e);
            const uint4 hv = *(const uint4*)(hbs + (long)d * HID_C + l * 8);
            den = ws;
            A[0] = ws * bflo(hv.x); A[1] = ws * bfhi(hv.x);
            A[2] = ws * bflo(hv.y); A[3] = ws * bfhi(hv.y);
            A[4] = ws * bflo(hv.z); A[5] = ws * bfhi(hv.z);
            A[6] = ws * bflo(hv.w); A[7] = ws * bfhi(hv.w);
        }
        const int beg = rp[dloc], fin = rp[dloc + 1];
        for (int j = beg + g8; j < fin; j += 16) {
            const int  j1   = j + 8;
            const bool has1 = j1 < fin;
            const unsigned r0 = srtL[j];
            const unsigned r1 = srtL[has1 ? j1 : j];
            const int   s0 = r0 & 0xFFFF;
            const int   s1 = r1 & 0xFFFF;
            const float as0 = a_src[s0];
            const float as1 = a_src[s1];
            const uint4 h0 = *(const uint4*)(hbs + (long)s0 * HID_C + l * 8);
            const uint4 h1 = *(const uint4*)(hbs + (long)s1 * HID_C + l * 8);
            float e0 = as0 + ad; e0 = (e0 >= 0.f) ? e0 : NEG_SLOPE * e0;
            float e1 = as1 + ad; e1 = (e1 >= 0.f) ? e1 : NEG_SLOPE * e1;
            const float w0 = __expf(e0);
            const float w1 = has1 ? __expf(e1) : 0.f;
            den += w0 + w1;
            A[0] = fmaf(w0, bflo(h0.x), A[0]); A[1] = fmaf(w0, bfhi(h0.x), A[1]);
            A[2] = fmaf(w0, bflo(h0.y), A[2]); A[3] = fmaf(w0, bfhi(h0.y), A[3]);
            A[4] = fmaf(w0, bflo(h0.z), A[4]); A[5] = fmaf(w0, bfhi(h0.z), A[5]);
            A[6] = fmaf(w0, bflo(h0.w), A[6]); A[7] = fmaf(w0, bfhi(h0.w), A[7]);
            A[0] = fmaf(w1, bflo(h1.x), A[0]); A[1] = fmaf(w1, bfhi(h1.x), A[1]);
            A[2] = fmaf(w1, bflo(h1.y), A[2]); A[3] = fmaf(w1, bfhi(h1.y), A[3]);
            A[4] = fmaf(w1, bflo(h1.z), A[4]); A[5] = fmaf(w1, bfhi(h1.z), A[5]);
            A[6] = fmaf(w1, bflo(h1.w), A[6]); A[7] = fmaf(w1, bfhi(h1.w), A[7]);
        }
#pragma unroll
        for (int off = 8; off <= 32; off <<= 1) {
#pragma unroll
            for (int k = 0; k < 8; ++k) A[k] += __shfl_xor(A[k], off, 64);
            den += __shfl_xor(den, off, 64);
        }
        const float rd = 1.0f / (den + 1e-16f);
        float p0 = 0.f, p1 = 0.f, p2 = 0.f, p3 = 0.f;
#pragma unroll
        for (int kc = 0; kc < 8; ++kc) {
            float vv = fmaf(A[kc], rd, biasR[kc]);
            vv = vv > 0.f ? vv : 0.f;
            p0 = fmaf(vv, Wr[kc][0], p0);
            p1 = fmaf(vv, Wr[kc][1], p1);
            p2 = fmaf(vv, Wr[kc][2], p2);
            p3 = fmaf(vv, Wr[kc][3], p3);
        }
#pragma unroll
        for (int off = 1; off <= 4; off <<= 1) {
            p0 += __shfl_xor(p0, off, 64);
            p1 += __shfl_xor(p1, off, 64);
            p2 += __shfl_xor(p2, off, 64);
            p3 += __shfl_xor(p3, off, 64);
        }
        if (l == 0) {
            float4 o = make_float4(p0 + blinR[0], p1 + blinR[1],
                                   p2 + blinR[2], p3 + blinR[3]);
            *(float4*)(out + (long)d * OUT_C + g8 * 4) = o;
        }
    }
}

// ---------------------------------------------------------------------------
extern "C" void kernel_launch(void* const* d_in, const int* in_sizes, int n_in,
                              void* d_out, int out_size, void* d_ws, size_t ws_size,
                              hipStream_t stream) {
    const float* x         = (const float*)d_in[0];
    const int*   ei        = (const int*)d_in[1];
    const float* W         = (const float*)d_in[2];
    const float* att_src   = (const float*)d_in[3];
    const float* att_dst   = (const float*)d_in[4];
    const float* bias_conv = (const float*)d_in[5];
    const float* W_lin     = (const float*)d_in[6];
    const float* b_lin     = (const float*)d_in[7];
    float*       out       = (float*)d_out;

    const int n_nodes = in_sizes[0] / IN_C;              // 50000
    const int E       = in_sizes[1] / 2;                 // 800000
    const int B1   = (E + EPB1 - 1) / EPB1;              // 391 bin1 blocks
    const int Q    = (n_nodes + BUCKETW - 1) / BUCKETW;  // 782 regions
    const int NSUP = (n_nodes + SUPW - 1) / SUPW;        // 49 supers
    const int NG   = (n_nodes + 15) / 16;                // 3125 gemm blocks

    // workspace layout (bcur1 ++ bcur2 contiguous -> one memset)
    __hip_bfloat16* hb = (__hip_bfloat16*)d_ws;              // N*64 bf16 (6.4MB)
    float* a_src   = (float*)(hb + (long)n_nodes * HID_C);   // N f
    float* a_dst   = a_src + n_nodes;                        // N f
    int*   bcur1   = (int*)(a_dst + n_nodes);                // NSUP*CSTRIDE
    int*   bcur2   = bcur1 + NSUP * CSTRIDE;                 // Q*CSTRIDE
    unsigned* superbuf  = (unsigned*)(bcur2 + (long)Q * CSTRIDE); // 3.6MB
    unsigned* bucketbuf = superbuf + (long)NSUP * RCAP1;          // 4.8MB

    // 0) zero both cursor arrays in one stream-ordered memset
    hipMemsetAsync(bcur1, 0,
                   (size_t)(NSUP + Q) * CSTRIDE * sizeof(int), stream);

    // 1) FUSED: gemm+logits (blocks 0..NG-1)  ||  bin1 (blocks NG..NG+B1-1)
    gemm_bin1_kernel<<<NG + B1, 256, 0, stream>>>(
        x, W, att_src, att_dst, hb, a_src, a_dst,
        ei, E, bcur1, superbuf, NG, n_nodes);

    // 2) bin level 2: super-buckets -> regions
    bin2_kernel<<<NSUP * PARTS, 256, 0, stream>>>(
        superbuf, bcur1, bcur2, bucketbuf);

    // 3) per-region aggregation + register epilogue (1024 thr = 16 waves)
    bucket_agg_kernel<<<Q, 1024, 0, stream>>>(
        bucketbuf, bcur2, hb, a_src, a_dst,
        bias_conv, W_lin, b_lin, out, n_nodes);
}

// Round 20
// 154.528 us; speedup vs baseline: 1.0788x; 1.0788x over previous
//
#include <hip/hip_runtime.h>
#include <hip/hip_bf16.h>

#define IN_C  128
#define HID_C 64
#define OUT_C 32
#define NEG_SLOPE 0.2f
#define EPB1    2048     // edges per bin1 block
#define EPB2    2048     // records per bin2 part
#define BUCKETW 64       // dst nodes per region
#define RCAP    1536     // region capacity (mean 1023, +16 sigma)
#define SUPW    1024     // dst nodes per super-bucket
#define RCAP1   18432    // super capacity (mean 16327)
#define PARTS   9        // bin2 parts per super
#define CSTRIDE 16       // cursor padding (64B) to spread atomic lines
#define XS_LD   136      // LDS x-tile leading dim (ushorts): bank-spread pad

typedef short bf16x8 __attribute__((ext_vector_type(8)));
typedef float f32x4  __attribute__((ext_vector_type(4)));

__device__ __forceinline__ unsigned short f2bf(float f) {
    __hip_bfloat16 h = __float2bfloat16(f);
    return *(unsigned short*)&h;
}
__device__ __forceinline__ float bflo(unsigned int u) {
    return __uint_as_float(u << 16);
}
__device__ __forceinline__ float bfhi(unsigned int u) {
    return __uint_as_float(u & 0xffff0000u);
}

// ---------------------------------------------------------------------------
// Kernel 1 (FUSED, R18 proven): blocks [0, ngemm) = gemm+logits tile;
// blocks [ngemm, ngemm+nbin) = bin1 edge-binning (pure int).
// bcur1 pre-zeroed by hipMemsetAsync.
// ---------------------------------------------------------------------------
__global__ __launch_bounds__(256) void gemm_bin1_kernel(
    const float* __restrict__ x, const float* __restrict__ W,
    const float* __restrict__ att_src, const float* __restrict__ att_dst,
    __hip_bfloat16* __restrict__ hb,
    float* __restrict__ a_src, float* __restrict__ a_dst,
    const int* __restrict__ ei, int E,
    int* __restrict__ bcur1, unsigned* __restrict__ superbuf,
    int ngemm, int n_nodes)
{
    __shared__ __align__(16) unsigned char smem[8960];
    const int t = threadIdx.x;

    if ((int)blockIdx.x < ngemm) {
        // ---------------- gemm path ----------------
        unsigned short* xs = (unsigned short*)smem;          // 4352 B
        float (*redA)[16] = (float(*)[16])(smem + 4352);     // 256 B
        float (*redD)[16] = (float(*)[16])(smem + 4608);     // 256 B
        const int wv   = t >> 6;
        const int lane = t & 63;
        const int m16  = lane & 15;
        const int quad = lane >> 4;
        const int node0 = blockIdx.x * 16;
        const int nrows = min(16, n_nodes - node0);

        const int ncol = wv * 16 + m16;
        bf16x8 B[4];
#pragma unroll
        for (int k0 = 0; k0 < 4; ++k0)
#pragma unroll
            for (int j = 0; j < 8; ++j)
                B[k0][j] = (short)f2bf(W[(k0 * 32 + quad * 8 + j) * HID_C + ncol]);

        {
            const float4* xg = (const float4*)(x + (long)node0 * IN_C);
#pragma unroll
            for (int i = t; i < 512; i += 256) {
                const int row = i >> 5;
                const int c4  = i & 31;
                float4 v = (row < nrows) ? xg[i] : make_float4(0.f, 0.f, 0.f, 0.f);
                ushort4 u;
                u.x = f2bf(v.x); u.y = f2bf(v.y);
                u.z = f2bf(v.z); u.w = f2bf(v.w);
                *(ushort4*)(xs + row * XS_LD + c4 * 4) = u;
            }
        }
        __syncthreads();

        f32x4 C = {0.f, 0.f, 0.f, 0.f};
#pragma unroll
        for (int k0 = 0; k0 < 4; ++k0) {
            const bf16x8 A = *(const bf16x8*)(xs + m16 * XS_LD + k0 * 32 + quad * 8);
            C = __builtin_amdgcn_mfma_f32_16x16x32_bf16(A, B[k0], C, 0, 0, 0);
        }

#pragma unroll
        for (int r = 0; r < 4; ++r) {
            const int row = quad * 4 + r;
            if (row < nrows)
                hb[(long)(node0 + row) * HID_C + ncol] = __float2bfloat16(C[r]);
        }

        {
            const float av = att_src[ncol];
            const float dv = att_dst[ncol];
            float ps[4], pd[4];
#pragma unroll
            for (int r = 0; r < 4; ++r) { ps[r] = C[r] * av; pd[r] = C[r] * dv; }
#pragma unroll
            for (int off = 1; off <= 8; off <<= 1) {
#pragma unroll
                for (int r = 0; r < 4; ++r) {
                    ps[r] += __shfl_xor(ps[r], off, 64);
                    pd[r] += __shfl_xor(pd[r], off, 64);
                }
            }
            if (m16 == 0) {
#pragma unroll
                for (int r = 0; r < 4; ++r) {
                    redA[wv][quad * 4 + r] = ps[r];
                    redD[wv][quad * 4 + r] = pd[r];
                }
            }
        }
        __syncthreads();
        if (t < 16 && t < nrows) {
            a_src[node0 + t] = redA[0][t] + redA[1][t] + redA[2][t] + redA[3][t];
            a_dst[node0 + t] = redD[0][t] + redD[1][t] + redD[2][t] + redD[3][t];
        }
    } else {
        // ---------------- bin1 path (pure int) ----------------
        unsigned* stage = (unsigned*)smem;                   // 8192 B
        int* excl = (int*)(smem + 8192);
        int* cur  = (int*)(smem + 8448);
        int* gpos = (int*)(smem + 8704);

        const int base = (blockIdx.x - ngemm) * EPB1;
        const int nedge = min(EPB1, E - base);

        if (t < 64) excl[t] = 0;
        __syncthreads();

        for (int i = t; i < nedge; i += 256)
            atomicAdd(&excl[ei[E + base + i] >> 10], 1);
        __syncthreads();

        if (t < 64) {
            int c = excl[t], incl = c;
#pragma unroll
            for (int off = 1; off <= 32; off <<= 1) {
                int u = __shfl_up(incl, off, 64);
                if (t >= off) incl += u;
            }
            excl[t] = incl - c;
            cur[t]  = incl - c;
        }
        __syncthreads();

        for (int i = t; i < nedge; i += 256) {
            const int s = ei[base + i];
            const int d = ei[E + base + i];
            const int sq = d >> 10;
            const int pos = atomicAdd(&cur[sq], 1);
            stage[pos] = (unsigned)s | ((unsigned)(d & 1023) << 16)
                         | ((unsigned)sq << 26);
        }
        __syncthreads();

        if (t < 64) {
            const int c = cur[t] - excl[t];
            gpos[t] = (c > 0) ? atomicAdd(&bcur1[t * CSTRIDE], c) : 0;
        }
        __syncthreads();

        for (int i = t; i < nedge; i += 256) {
            const unsigned r = stage[i];
            const int sq = r >> 26;
            const int dp = gpos[sq] + (i - excl[sq]);
            if (dp < RCAP1) superbuf[(long)sq * RCAP1 + dp] = r;
        }
    }
}

// ---------------------------------------------------------------------------
// Kernel 2 (bin level 2, R16/R18 proven): super-buckets -> 64-dst regions.
// ---------------------------------------------------------------------------
__global__ __launch_bounds__(256) void bin2_kernel(
    const unsigned* __restrict__ superbuf, const int* __restrict__ bcur1,
    int* __restrict__ bcur2, unsigned* __restrict__ bucketbuf)
{
    __shared__ unsigned srt[EPB2];   // 8 KB
    __shared__ int cnt[16];
    __shared__ int rp[16];
    __shared__ int cur16[16];
    __shared__ int gpos[16];

    const int t    = threadIdx.x;
    const int sq   = blockIdx.x / PARTS;
    const int part = blockIdx.x % PARTS;
    const int tot  = min(bcur1[sq * CSTRIDE], RCAP1);
    const int beg  = part * EPB2;
    const int n    = min(EPB2, tot - beg);
    if (n <= 0) return;                       // block-uniform

    if (t < 16) cnt[t] = 0;
    __syncthreads();

    const unsigned* src = superbuf + (long)sq * RCAP1 + beg;

    for (int i = t; i < n; i += 256)
        atomicAdd(&cnt[(src[i] >> 22) & 15], 1);
    __syncthreads();

    if (t == 0) {
        int run = 0;
#pragma unroll
        for (int k = 0; k < 16; ++k) { rp[k] = run; cur16[k] = run; run += cnt[k]; }
    }
    __syncthreads();

    for (int i = t; i < n; i += 256) {
        const unsigned r = src[i];
        const int pos = atomicAdd(&cur16[(r >> 22) & 15], 1);
        srt[pos] = r;
    }
    __syncthreads();

    if (t < 16) {
        const int c = cnt[t];
        const int q2 = sq * 16 + t;
        gpos[t] = (c > 0) ? atomicAdd(&bcur2[q2 * CSTRIDE], c) : 0;
    }
    __syncthreads();

    for (int i = t; i < n; i += 256) {
        const unsigned r = srt[i];
        const int idx = (r >> 22) & 15;
        const int dp  = gpos[idx] + (i - rp[idx]);
        const int q2  = sq * 16 + idx;
        const unsigned nx = (r & 0xFFFFu) | (((r >> 16) & 63u) << 16);
        if (dp < RCAP) bucketbuf[(long)q2 * RCAP + dp] = nx;
    }
}

// ---------------------------------------------------------------------------
// Kernel 3 (R16/R18 proven): per-region aggregation + register epilogue;
// 4-byte records; w computed inline. 512 threads = 8 waves/region.
// ---------------------------------------------------------------------------
__global__ __launch_bounds__(512) void bucket_agg_kernel(
    const unsigned* __restrict__ bucketbuf, const int* __restrict__ bcursor,
    const __hip_bfloat16* __restrict__ hb,
    const float* __restrict__ a_src, const float* __restrict__ a_dst,
    const float* __restrict__ bias_conv,
    const float* __restrict__ W_lin, const float* __restrict__ b_lin,
    float* __restrict__ out, int n_nodes)
{
    __shared__ unsigned srtL[RCAP];     // 6 KB
    __shared__ int cntd[BUCKETW];
    __shared__ int rp[BUCKETW + 1];
    __shared__ int curd[BUCKETW];

    const int t  = threadIdx.x;
    const int q  = blockIdx.x;
    const int d0 = q * BUCKETW;
    const int dmax = min(BUCKETW, n_nodes - d0);
    const int tot  = min(bcursor[q * CSTRIDE], RCAP);
    const int wv = t >> 6, lane = t & 63, g8 = lane >> 3, l = lane & 7;

    if (t < BUCKETW) cntd[t] = 0;
    __syncthreads();

    const unsigned* gsrc = bucketbuf + (long)q * RCAP;

    // pass 1: count per dloc
    for (int i = t; i < tot; i += 512)
        atomicAdd(&cntd[(gsrc[i] >> 16) & 63], 1);
    __syncthreads();

    // one-wave scan of 64 counters
    if (t < 64) {
        int c = cntd[t], incl = c;
#pragma unroll
        for (int off = 1; off <= 32; off <<= 1) {
            int u = __shfl_up(incl, off, 64);
            if (t >= off) incl += u;
        }
        rp[t] = incl - c;
        curd[t] = incl - c;
        if (t == 63) rp[64] = incl;
    }
    __syncthreads();

    // pass 2: scatter into sorted LDS order (second read is L2-hot)
    for (int i = t; i < tot; i += 512) {
        const unsigned r = gsrc[i];
        const int pos = atomicAdd(&curd[(r >> 16) & 63], 1);
        srtL[pos] = r;
    }
    __syncthreads();

    // per-lane epilogue constants
    float Wr[8][4];
#pragma unroll
    for (int kc = 0; kc < 8; ++kc)
#pragma unroll
        for (int kj = 0; kj < 4; ++kj)
            Wr[kc][kj] = W_lin[(l * 8 + kc) * OUT_C + g8 * 4 + kj];
    float biasR[8];
#pragma unroll
    for (int kc = 0; kc < 8; ++kc) biasR[kc] = bias_conv[l * 8 + kc];
    float blinR[4];
#pragma unroll
    for (int kj = 0; kj < 4; ++kj) blinR[kj] = b_lin[g8 * 4 + kj];

    const unsigned short* hbs = (const unsigned short*)hb;

    for (int dloc = wv; dloc < dmax; dloc += 8) {
        const int d = d0 + dloc;
        const float ad = a_dst[d];
        float A[8] = {0.f,0.f,0.f,0.f,0.f,0.f,0.f,0.f};
        float den = 0.f;
        if (g8 == 0) {        // self-loop on slot 0
            float e = a_src[d] + ad;
            e = (e >= 0.f) ? e : NEG_SLOPE * e;
            const float ws = __expf(e);
            const uint4 hv = *(const uint4*)(hbs + (long)d * HID_C + l * 8);
            den = ws;
            A[0] = ws * bflo(hv.x); A[1] = ws * bfhi(hv.x);
            A[2] = ws * bflo(hv.y); A[3] = ws * bfhi(hv.y);
            A[4] = ws * bflo(hv.z); A[5] = ws * bfhi(hv.z);
            A[6] = ws * bflo(hv.w); A[7] = ws * bfhi(hv.w);
        }
        const int beg = rp[dloc], fin = rp[dloc + 1];
        for (int j = beg + g8; j < fin; j += 16) {
            const int  j1   = j + 8;
            const bool has1 = j1 < fin;
            const unsigned r0 = srtL[j];
            const unsigned r1 = srtL[has1 ? j1 : j];
            const int   s0 = r0 & 0xFFFF;
            const int   s1 = r1 & 0xFFFF;
            const float as0 = a_src[s0];
            const float as1 = a_src[s1];
            const uint4 h0 = *(const uint4*)(hbs + (long)s0 * HID_C + l * 8);
            const uint4 h1 = *(const uint4*)(hbs + (long)s1 * HID_C + l * 8);
            float e0 = as0 + ad; e0 = (e0 >= 0.f) ? e0 : NEG_SLOPE * e0;
            float e1 = as1 + ad; e1 = (e1 >= 0.f) ? e1 : NEG_SLOPE * e1;
            const float w0 = __expf(e0);
            const float w1 = has1 ? __expf(e1) : 0.f;
            den += w0 + w1;
            A[0] = fmaf(w0, bflo(h0.x), A[0]); A[1] = fmaf(w0, bfhi(h0.x), A[1]);
            A[2] = fmaf(w0, bflo(h0.y), A[2]); A[3] = fmaf(w0, bfhi(h0.y), A[3]);
            A[4] = fmaf(w0, bflo(h0.z), A[4]); A[5] = fmaf(w0, bfhi(h0.z), A[5]);
            A[6] = fmaf(w0, bflo(h0.w), A[6]); A[7] = fmaf(w0, bfhi(h0.w), A[7]);
            A[0] = fmaf(w1, bflo(h1.x), A[0]); A[1] = fmaf(w1, bfhi(h1.x), A[1]);
            A[2] = fmaf(w1, bflo(h1.y), A[2]); A[3] = fmaf(w1, bfhi(h1.y), A[3]);
            A[4] = fmaf(w1, bflo(h1.z), A[4]); A[5] = fmaf(w1, bfhi(h1.z), A[5]);
            A[6] = fmaf(w1, bflo(h1.w), A[6]); A[7] = fmaf(w1, bfhi(h1.w), A[7]);
        }
#pragma unroll
        for (int off = 8; off <= 32; off <<= 1) {
#pragma unroll
            for (int k = 0; k < 8; ++k) A[k] += __shfl_xor(A[k], off, 64);
            den += __shfl_xor(den, off, 64);
        }
        const float rd = 1.0f / (den + 1e-16f);
        float p0 = 0.f, p1 = 0.f, p2 = 0.f, p3 = 0.f;
#pragma unroll
        for (int kc = 0; kc < 8; ++kc) {
            float vv = fmaf(A[kc], rd, biasR[kc]);
            vv = vv > 0.f ? vv : 0.f;
            p0 = fmaf(vv, Wr[kc][0], p0);
            p1 = fmaf(vv, Wr[kc][1], p1);
            p2 = fmaf(vv, Wr[kc][2], p2);
            p3 = fmaf(vv, Wr[kc][3], p3);
        }
#pragma unroll
        for (int off = 1; off <= 4; off <<= 1) {
            p0 += __shfl_xor(p0, off, 64);
            p1 += __shfl_xor(p1, off, 64);
            p2 += __shfl_xor(p2, off, 64);
            p3 += __shfl_xor(p3, off, 64);
        }
        if (l == 0) {
            float4 o = make_float4(p0 + blinR[0], p1 + blinR[1],
                                   p2 + blinR[2], p3 + blinR[3]);
            *(float4*)(out + (long)d * OUT_C + g8 * 4) = o;
        }
    }
}

// ---------------------------------------------------------------------------
extern "C" void kernel_launch(void* const* d_in, const int* in_sizes, int n_in,
                              void* d_out, int out_size, void* d_ws, size_t ws_size,
                              hipStream_t stream) {
    const float* x         = (const float*)d_in[0];
    const int*   ei        = (const int*)d_in[1];
    const float* W         = (const float*)d_in[2];
    const float* att_src   = (const float*)d_in[3];
    const float* att_dst   = (const float*)d_in[4];
    const float* bias_conv = (const float*)d_in[5];
    const float* W_lin     = (const float*)d_in[6];
    const float* b_lin     = (const float*)d_in[7];
    float*       out       = (float*)d_out;

    const int n_nodes = in_sizes[0] / IN_C;              // 50000
    const int E       = in_sizes[1] / 2;                 // 800000
    const int B1   = (E + EPB1 - 1) / EPB1;              // 391 bin1 blocks
    const int Q    = (n_nodes + BUCKETW - 1) / BUCKETW;  // 782 regions
    const int NSUP = (n_nodes + SUPW - 1) / SUPW;        // 49 supers
    const int NG   = (n_nodes + 15) / 16;                // 3125 gemm blocks

    // workspace layout (bcur1 ++ bcur2 contiguous -> one memset)
    __hip_bfloat16* hb = (__hip_bfloat16*)d_ws;              // N*64 bf16 (6.4MB)
    float* a_src   = (float*)(hb + (long)n_nodes * HID_C);   // N f
    float* a_dst   = a_src + n_nodes;                        // N f
    int*   bcur1   = (int*)(a_dst + n_nodes);                // NSUP*CSTRIDE
    int*   bcur2   = bcur1 + NSUP * CSTRIDE;                 // Q*CSTRIDE
    unsigned* superbuf  = (unsigned*)(bcur2 + (long)Q * CSTRIDE); // 3.6MB
    unsigned* bucketbuf = superbuf + (long)NSUP * RCAP1;          // 4.8MB

    // 0) zero both cursor arrays in one stream-ordered memset
    hipMemsetAsync(bcur1, 0,
                   (size_t)(NSUP + Q) * CSTRIDE * sizeof(int), stream);

    // 1) FUSED: gemm+logits (blocks 0..NG-1)  ||  bin1 (blocks NG..NG+B1-1)
    gemm_bin1_kernel<<<NG + B1, 256, 0, stream>>>(
        x, W, att_src, att_dst, hb, a_src, a_dst,
        ei, E, bcur1, superbuf, NG, n_nodes);

    // 2) bin level 2: super-buckets -> regions
    bin2_kernel<<<NSUP * PARTS, 256, 0, stream>>>(
        superbuf, bcur1, bcur2, bucketbuf);

    // 3) per-region aggregation + register epilogue (512 thr = 8 waves)
    bucket_agg_kernel<<<Q, 512, 0, stream>>>(
        bucketbuf, bcur2, hb, a_src, a_dst,
        bias_conv, W_lin, b_lin, out, n_nodes);
}